// Round 11
// baseline (433.303 us; speedup 1.0000x reference)
//
#include <hip/hip_runtime.h>
#include <hip/hip_bf16.h>
#include <math.h>

// EncoderLayer_68186900791439 — graph transformer encoder layer on MI355X.
// Round 11: attn softmax without max-tracking (logits bounded ~|10| with LN'd
// inputs -> exp() safe in f32; identical math to reference's max-subtracted
// softmax). Saves ~25-30% of per-edge VALU (r10: VALUBusy 70%). Scale folded
// into q; __expf; slot merge is now plain adds. Everything else = round 10.

typedef unsigned short u16;
using short8 = __attribute__((ext_vector_type(8))) short;
using f32x4  = __attribute__((ext_vector_type(4))) float;
using f32x2  = __attribute__((ext_vector_type(2))) float;

__device__ __forceinline__ float bf2f(u16 u) {
    return __uint_as_float(((unsigned int)u) << 16);
}
__device__ __forceinline__ u16 f2bf(float f) {
    __hip_bfloat16 h = __float2bfloat16(f);
    return __builtin_bit_cast(u16, h);
}
__device__ __forceinline__ float bfe(short8 v, int j) {
    return bf2f((u16)v[j]);
}
// decode 4 packed fp8-e4m3 (one dword) -> 4 f32 (HW cvt, OCP on gfx950)
__device__ __forceinline__ void fp8x4_to_f32(int w, float* out) {
    f32x2 lo = __builtin_amdgcn_cvt_pk_f32_fp8(w, false);
    f32x2 hi = __builtin_amdgcn_cvt_pk_f32_fp8(w, true);
    out[0] = lo[0]; out[1] = lo[1]; out[2] = hi[0]; out[3] = hi[1];
}
// pack 4 f32 -> 4 fp8-e4m3 bytes in one dword
__device__ __forceinline__ unsigned pack_fp8x4(float4 f) {
    unsigned w = 0;
    w = (unsigned)__builtin_amdgcn_cvt_pk_fp8_f32(f.x, f.y, (int)w, false);
    w = (unsigned)__builtin_amdgcn_cvt_pk_fp8_f32(f.z, f.w, (int)w, true);
    return w;
}

// ============ Kernel A: prep weights + bias concat + LN1 + zero cnt ==========
__global__ __launch_bounds__(256) void fused_prep_ln(
    const float* __restrict__ x, const float* __restrict__ ln1g,
    const float* __restrict__ ln1b,
    const float* __restrict__ Wq, const float* __restrict__ Wk,
    const float* __restrict__ Wv, const float* __restrict__ Ws,
    const float* __restrict__ W1, const float* __restrict__ W2,
    const float* __restrict__ bq, const float* __restrict__ bk,
    const float* __restrict__ bv, const float* __restrict__ bs,
    u16* __restrict__ wt, float* __restrict__ bc,
    u16* __restrict__ y, int* __restrict__ cnt, int n)
{
    int gsz = gridDim.x * 256;
    int gtid = blockIdx.x * 256 + threadIdx.x;

    for (int i = gtid; i < 147456 + 896; i += gsz) {
        if (i < 147456) {
            const float* W; int N; int base;
            if      (i <  32768) { W = Wq; N = 256; base = 0; }
            else if (i <  65536) { W = Wk; N = 256; base = 32768; }
            else if (i <  98304) { W = Wv; N = 256; base = 65536; }
            else if (i < 114688) { W = Ws; N = 128; base = 98304; }
            else if (i < 131072) { W = W1; N = 128; base = 114688; }
            else                 { W = W2; N = 128; base = 131072; }
            int j = i - base;
            int nIdx = j >> 7, k = j & 127;
            wt[i] = f2bf(W[(size_t)k * N + nIdx]);
        } else {
            int j = i - 147456;
            float v;
            if      (j < 256) v = bq[j];
            else if (j < 512) v = bk[j - 256];
            else if (j < 768) v = bv[j - 512];
            else              v = bs[j - 768];
            bc[j] = v;
        }
    }
    for (int i = gtid; i < n; i += gsz) cnt[i] = 0;
    int lane = threadIdx.x & 63;
    int gw = gtid >> 6, nw = gsz >> 6;
    for (int row = gw; row < n; row += nw) {
        size_t base = (size_t)row * 128;
        float v0 = x[base + lane];
        float v1 = x[base + 64 + lane];
        float s1 = v0 + v1, s2 = v0 * v0 + v1 * v1;
        for (int o = 1; o <= 32; o <<= 1) {
            s1 += __shfl_xor(s1, o);
            s2 += __shfl_xor(s2, o);
        }
        float mu = s1 * (1.f / 128.f);
        float var = s2 * (1.f / 128.f) - mu * mu;
        float rstd = rsqrtf(var + 1e-5f);
        y[base + lane]      = f2bf((v0 - mu) * rstd * ln1g[lane] + ln1b[lane]);
        y[base + 64 + lane] = f2bf((v1 - mu) * rstd * ln1g[64 + lane] + ln1b[64 + lane]);
    }
}

// ============================ CSR build ====================================
__global__ __launch_bounds__(256) void hist_kernel(const int* __restrict__ dst,
                                                   int* __restrict__ cnt, int e) {
    int stride = gridDim.x * 256;
    for (int i = blockIdx.x * 256 + threadIdx.x; i < e; i += stride)
        atomicAdd(&cnt[dst[i]], 1);
}

__global__ __launch_bounds__(256) void scan_block_sum(const int* __restrict__ cnt,
                                                      int* __restrict__ bsum, int n) {
    __shared__ int s[256];
    int idx = blockIdx.x * 256 + threadIdx.x;
    s[threadIdx.x] = (idx < n) ? cnt[idx] : 0;
    __syncthreads();
    for (int o = 128; o > 0; o >>= 1) {
        if (threadIdx.x < o) s[threadIdx.x] += s[threadIdx.x + o];
        __syncthreads();
    }
    if (threadIdx.x == 0) bsum[blockIdx.x] = s[0];
}
__global__ __launch_bounds__(256) void scan_partials(const int* __restrict__ bsum,
                                                     int* __restrict__ bsumex, int nb) {
    __shared__ int s[256];
    int t = threadIdx.x;
    int v = (t < nb) ? bsum[t] : 0;
    s[t] = v;
    __syncthreads();
    for (int o = 1; o < 256; o <<= 1) {
        int add = (t >= o) ? s[t - o] : 0;
        __syncthreads();
        s[t] += add;
        __syncthreads();
    }
    bsumex[t] = s[t] - v;
}
__global__ __launch_bounds__(256) void scan_write(const int* __restrict__ cnt,
                                                  const int* __restrict__ bsumex,
                                                  int* __restrict__ rowptr,
                                                  int* __restrict__ cursor, int n, int etot) {
    __shared__ int s[256];
    int t = threadIdx.x;
    int idx = blockIdx.x * 256 + t;
    int v = (idx < n) ? cnt[idx] : 0;
    s[t] = v;
    __syncthreads();
    for (int o = 1; o < 256; o <<= 1) {
        int add = (t >= o) ? s[t - o] : 0;
        __syncthreads();
        s[t] += add;
        __syncthreads();
    }
    if (idx < n) {
        int ex = bsumex[blockIdx.x] + s[t] - v;
        rowptr[idx] = ex;
        cursor[idx] = ex;
    }
    if (idx == 0) rowptr[n] = etot;
}

__global__ __launch_bounds__(256) void scatter_kernel(const int* __restrict__ dst,
                                                      const int* __restrict__ src,
                                                      int* __restrict__ cursor,
                                                      int* __restrict__ esrc, int e) {
    int stride = gridDim.x * 256;
    for (int i = blockIdx.x * 256 + threadIdx.x; i < e; i += stride) {
        int p = atomicAdd(&cursor[dst[i]], 1);
        esrc[p] = src[i];
    }
}

// =============== MFMA GEMM: qkv+skip — LDS epilogue, coalesced stores =========
__global__ __launch_bounds__(256) void qkv_gemm(
    const u16* __restrict__ A, const u16* __restrict__ Bt,
    const float* __restrict__ bias, u16* __restrict__ qkv,
    float* __restrict__ skip, int n)
{
    __shared__ float tile[64 * 132];                 // 33.8 KB
    int wid = threadIdx.x >> 6, lane = threadIdx.x & 63;
    int wr = wid >> 1, wc = wid & 1;
    int r0 = blockIdx.x * 64;
    int c0 = blockIdx.y * 128;
    int lm = lane & 15, quad = lane >> 4;

    const u16* aBase = A  + (size_t)(r0 + wr * 32 + lm) * 128 + quad * 8;
    const u16* bBase = Bt + (size_t)(c0 + wc * 64 + lm) * 128 + quad * 8;

    f32x4 acc[2][4] = {};
#pragma unroll
    for (int kk = 0; kk < 128; kk += 32) {
        short8 a0 = *(const short8*)(aBase + kk);
        short8 a1 = *(const short8*)(aBase + 16 * 128 + kk);
#pragma unroll
        for (int j = 0; j < 4; ++j) {
            short8 bj = *(const short8*)(bBase + (size_t)j * 16 * 128 + kk);
            acc[0][j] = __builtin_amdgcn_mfma_f32_16x16x32_bf16(a0, bj, acc[0][j], 0, 0, 0);
            acc[1][j] = __builtin_amdgcn_mfma_f32_16x16x32_bf16(a1, bj, acc[1][j], 0, 0, 0);
        }
    }
#pragma unroll
    for (int j = 0; j < 4; ++j) {
        int colL = wc * 64 + j * 16 + lm;
        float bv = bias[c0 + colL];
#pragma unroll
        for (int rt = 0; rt < 2; ++rt) {
#pragma unroll
            for (int i2 = 0; i2 < 4; ++i2) {
                int rowL = wr * 32 + rt * 16 + quad * 4 + i2;
                tile[rowL * 132 + colL] = acc[rt][j][i2] + bv;
            }
        }
    }
    __syncthreads();

    int rowL = threadIdx.x >> 2;
    int row  = r0 + rowL;
    if (row >= n) return;
    int ck = (threadIdx.x & 3) * 32;
    int cg = c0 + ck;
    float4 f[8];
#pragma unroll
    for (int k = 0; k < 8; ++k)
        f[k] = *(const float4*)&tile[rowL * 132 + ck + k * 4];

    if (c0 < 256) {                                   // q bf16
        u16* dst = qkv + (size_t)row * 640 + cg;
#pragma unroll
        for (int k = 0; k < 4; ++k) {
            short8 o;
            o[0] = (short)f2bf(f[2 * k].x);     o[1] = (short)f2bf(f[2 * k].y);
            o[2] = (short)f2bf(f[2 * k].z);     o[3] = (short)f2bf(f[2 * k].w);
            o[4] = (short)f2bf(f[2 * k + 1].x); o[5] = (short)f2bf(f[2 * k + 1].y);
            o[6] = (short)f2bf(f[2 * k + 1].z); o[7] = (short)f2bf(f[2 * k + 1].w);
            *(short8*)(dst + k * 8) = o;
        }
    } else if (c0 < 512) {                            // k fp8 e4m3, packed
        unsigned char* kb = (unsigned char*)qkv + (size_t)row * 1280 + 512 + (cg - 256);
        uint4 w0, w1;
        w0.x = pack_fp8x4(f[0]); w0.y = pack_fp8x4(f[1]);
        w0.z = pack_fp8x4(f[2]); w0.w = pack_fp8x4(f[3]);
        w1.x = pack_fp8x4(f[4]); w1.y = pack_fp8x4(f[5]);
        w1.z = pack_fp8x4(f[6]); w1.w = pack_fp8x4(f[7]);
        *(uint4*)kb = w0;
        *(uint4*)(kb + 16) = w1;
    } else if (c0 < 768) {                            // v bf16
        u16* dst = qkv + (size_t)row * 640 + (cg - 128);
#pragma unroll
        for (int k = 0; k < 4; ++k) {
            short8 o;
            o[0] = (short)f2bf(f[2 * k].x);     o[1] = (short)f2bf(f[2 * k].y);
            o[2] = (short)f2bf(f[2 * k].z);     o[3] = (short)f2bf(f[2 * k].w);
            o[4] = (short)f2bf(f[2 * k + 1].x); o[5] = (short)f2bf(f[2 * k + 1].y);
            o[6] = (short)f2bf(f[2 * k + 1].z); o[7] = (short)f2bf(f[2 * k + 1].w);
            *(short8*)(dst + k * 8) = o;
        }
    } else {                                          // skip f32
        float* dst = skip + (size_t)row * 128 + (cg - 768);
#pragma unroll
        for (int k = 0; k < 8; ++k)
            *(float4*)(dst + k * 4) = f[k];
    }
}

// =============== Attention: wave per dst, 2 edge slots, fp8 k ================
// No max-tracking: logits |alpha| <~ 10 with LN'd inputs -> exp() safe in f32;
// identical math to reference's max-subtracted softmax (ratio unchanged).
// Lane layout: slot=lane>>5, head=(lane>>4)&1, sub=lane&15. Lane owns 8 cols.
// Epilogue: slot add-merge + head-mean + skip + residual + LN2 -> y.
__global__ __launch_bounds__(256) void attn_kernel(
    const u16* __restrict__ qkv, const int* __restrict__ rowptr,
    const int* __restrict__ esrc, const float* __restrict__ x,
    float* __restrict__ sx, const float* __restrict__ g2,
    const float* __restrict__ b2, u16* __restrict__ y, int n)
{
    int wid = threadIdx.x >> 6, lane = threadIdx.x & 63;
    int i = blockIdx.x * 4 + wid;
    if (i >= n) return;
    int slot = lane >> 5;
    int sub  = lane & 15;
    int colOff = ((lane >> 4) & 1) * 128 + sub * 8;

    const float scale = 0.08838834764831845f;   // 1/sqrt(128), folded into q
    short8 q8 = *(const short8*)(qkv + (size_t)i * 640 + colOff);
    float qf[8];
#pragma unroll
    for (int j = 0; j < 8; ++j) qf[j] = bfe(q8, j) * scale;

    int beg = rowptr[i], end = rowptr[i + 1];
    float l = 0.f;
    float acc[8] = {};

    int t = beg + slot;
    for (; t + 2 < end; t += 4) {               // 2 edges per slot in flight
        int s0 = esrc[t], s1 = esrc[t + 2];
        const u16* n0 = qkv + (size_t)s0 * 640;
        const u16* n1 = qkv + (size_t)s1 * 640;
        uint2 kw0 = *(const uint2*)((const unsigned char*)(n0 + 256) + colOff);
        uint2 kw1 = *(const uint2*)((const unsigned char*)(n1 + 256) + colOff);
        short8 v0 = *(const short8*)(n0 + 384 + colOff);
        short8 v1 = *(const short8*)(n1 + 384 + colOff);
        float k0f[8], k1f[8];
        fp8x4_to_f32((int)kw0.x, k0f); fp8x4_to_f32((int)kw0.y, k0f + 4);
        fp8x4_to_f32((int)kw1.x, k1f); fp8x4_to_f32((int)kw1.y, k1f + 4);
        float d0 = 0.f, d1 = 0.f;
#pragma unroll
        for (int j = 0; j < 8; ++j) {
            d0 += qf[j] * k0f[j];
            d1 += qf[j] * k1f[j];
        }
#pragma unroll
        for (int o = 1; o <= 8; o <<= 1) {      // reduce over 16-lane group
            d0 += __shfl_xor(d0, o);
            d1 += __shfl_xor(d1, o);
        }
        float w0 = __expf(d0), w1 = __expf(d1);
        l += w0 + w1;
#pragma unroll
        for (int j = 0; j < 8; ++j)
            acc[j] += w0 * bfe(v0, j) + w1 * bfe(v1, j);
    }
    if (t < end) {                               // slot tail: single edge
        int s0 = esrc[t];
        const u16* n0 = qkv + (size_t)s0 * 640;
        uint2 kw0 = *(const uint2*)((const unsigned char*)(n0 + 256) + colOff);
        short8 v0 = *(const short8*)(n0 + 384 + colOff);
        float k0f[8];
        fp8x4_to_f32((int)kw0.x, k0f); fp8x4_to_f32((int)kw0.y, k0f + 4);
        float d0 = 0.f;
#pragma unroll
        for (int j = 0; j < 8; ++j) d0 += qf[j] * k0f[j];
#pragma unroll
        for (int o = 1; o <= 8; o <<= 1) d0 += __shfl_xor(d0, o);
        float w0 = __expf(d0);
        l += w0;
#pragma unroll
        for (int j = 0; j < 8; ++j) acc[j] += w0 * bfe(v0, j);
    }

    // merge the two slots: plain adds (no rescale needed)
    l += __shfl_xor(l, 32);
    float inv = (l > 0.f) ? (1.f / l) : 0.f;
#pragma unroll
    for (int j = 0; j < 8; ++j) {
        acc[j] = (acc[j] + __shfl_xor(acc[j], 32)) * inv;
        acc[j] = 0.5f * (acc[j] + __shfl_xor(acc[j], 16));  // head mean
    }

    if (lane < 16) {                             // lanes 0..15 hold the row
        size_t base = (size_t)i * 128 + sub * 8;
        float4 xv0 = *(const float4*)(x + base);
        float4 xv1 = *(const float4*)(x + base + 4);
        float4 sk0 = *(const float4*)(sx + base);
        float4 sk1 = *(const float4*)(sx + base + 4);
        float r[8];
        r[0] = xv0.x + sk0.x + acc[0]; r[1] = xv0.y + sk0.y + acc[1];
        r[2] = xv0.z + sk0.z + acc[2]; r[3] = xv0.w + sk0.w + acc[3];
        r[4] = xv1.x + sk1.x + acc[4]; r[5] = xv1.y + sk1.y + acc[5];
        r[6] = xv1.z + sk1.z + acc[6]; r[7] = xv1.w + sk1.w + acc[7];
        *(float4*)(sx + base)     = make_float4(r[0], r[1], r[2], r[3]);
        *(float4*)(sx + base + 4) = make_float4(r[4], r[5], r[6], r[7]);
        float s1 = 0.f, s2 = 0.f;
#pragma unroll
        for (int j = 0; j < 8; ++j) { s1 += r[j]; s2 += r[j] * r[j]; }
#pragma unroll
        for (int o = 1; o <= 8; o <<= 1) {
            s1 += __shfl_xor(s1, o);
            s2 += __shfl_xor(s2, o);
        }
        float mu = s1 * (1.f / 128.f);
        float var = s2 * (1.f / 128.f) - mu * mu;
        float rstd = rsqrtf(var + 1e-5f);
        short8 o8;
#pragma unroll
        for (int j = 0; j < 8; ++j)
            o8[j] = (short)f2bf((r[j] - mu) * rstd * g2[sub * 8 + j] + b2[sub * 8 + j]);
        *(short8*)(y + base) = o8;
    }
}

// =============== Fused FFN: out = x2 + gelu(y2@W1T+b1)@W2T+b2 ===============
__global__ __launch_bounds__(256) void ffn_kernel(
    const u16* __restrict__ y2, const u16* __restrict__ W1T,
    const float* __restrict__ b1, const u16* __restrict__ W2T,
    const float* __restrict__ b2, const float* __restrict__ x2,
    float* __restrict__ out, int n)
{
    __shared__ u16 t1[64 * 136];
    int wid = threadIdx.x >> 6, lane = threadIdx.x & 63;
    int lm = lane & 15, quad = lane >> 4;
    int r0 = blockIdx.x * 64 + wid * 16;

    const u16* aBase = y2 + (size_t)(r0 + lm) * 128 + quad * 8;
    f32x4 acc[8] = {};
#pragma unroll
    for (int kk = 0; kk < 128; kk += 32) {
        short8 a0 = *(const short8*)(aBase + kk);
#pragma unroll
        for (int j = 0; j < 8; ++j) {
            short8 bj = *(const short8*)(W1T + (size_t)(j * 16 + lm) * 128 + quad * 8 + kk);
            acc[j] = __builtin_amdgcn_mfma_f32_16x16x32_bf16(a0, bj, acc[j], 0, 0, 0);
        }
    }
#pragma unroll
    for (int j = 0; j < 8; ++j) {
        int col = j * 16 + lm;
        float bv = b1[col];
#pragma unroll
        for (int i2 = 0; i2 < 4; ++i2) {
            int rl = wid * 16 + quad * 4 + i2;
            float v = acc[j][i2] + bv;
            v = 0.5f * v * (1.f + erff(v * 0.70710678118654752f));
            t1[rl * 136 + col] = f2bf(v);
        }
    }
    __syncthreads();

    f32x4 acc2[8] = {};
#pragma unroll
    for (int kk = 0; kk < 128; kk += 32) {
        short8 a0 = *(const short8*)(t1 + (wid * 16 + lm) * 136 + quad * 8 + kk);
#pragma unroll
        for (int j = 0; j < 8; ++j) {
            short8 bj = *(const short8*)(W2T + (size_t)(j * 16 + lm) * 128 + quad * 8 + kk);
            acc2[j] = __builtin_amdgcn_mfma_f32_16x16x32_bf16(a0, bj, acc2[j], 0, 0, 0);
        }
    }
#pragma unroll
    for (int j = 0; j < 8; ++j) {
        int col = j * 16 + lm;
        float bv = b2[col];
#pragma unroll
        for (int i2 = 0; i2 < 4; ++i2) {
            int row = r0 + quad * 4 + i2;
            if (row >= n) continue;
            size_t ob = (size_t)row * 128 + col;
            out[ob] = acc2[j][i2] + bv + x2[ob];
        }
    }
}

extern "C" void kernel_launch(void* const* d_in, const int* in_sizes, int n_in,
                              void* d_out, int out_size, void* d_ws, size_t ws_size,
                              hipStream_t stream)
{
    const float* x    = (const float*)d_in[0];
    const int*   ei   = (const int*)d_in[1];

    int n = in_sizes[0] / 128;     // 50000
    int e = in_sizes[1] / 2;       // 800000
    const int* src  = ei;          // edge_index[0] (messages src -> dst)
    const int* dstp = ei + e;      // edge_index[1]

    char* w = (char*)d_ws;
    size_t off = 0;
    auto alloc = [&](size_t bytes) -> void* {
        void* p = w + off;
        off = (off + bytes + 255) & ~(size_t)255;
        return p;
    };
    u16*   y    = (u16*)alloc((size_t)n * 128 * 2);   // LN1 out, then LN2 out
    u16*   qkv  = (u16*)alloc((size_t)n * 640 * 2);   // q bf16 | k fp8 | v bf16
    float* sx   = (float*)alloc((size_t)n * 128 * 4); // skip, then x2 in-place
    u16*   wt   = (u16*)alloc((size_t)147456 * 2);
    float* bc   = (float*)alloc(896 * 4);
    int* cnt    = (int*)alloc((size_t)n * 4);
    int* cursor = (int*)alloc((size_t)n * 4);
    int* rowptr = (int*)alloc(((size_t)n + 1) * 4);
    int* esrc   = (int*)alloc((size_t)e * 4);
    int* bsum   = (int*)alloc(1024);
    int* bsumex = (int*)alloc(1024);

    int gr  = (n + 63) / 64;       // row blocks (qkv + ffn)
    int nb  = (n + 255) / 256;     // scan chunks (196)

    fused_prep_ln<<<2048, 256, 0, stream>>>(
        x, (const float*)d_in[2], (const float*)d_in[3],
        (const float*)d_in[4], (const float*)d_in[6], (const float*)d_in[8],
        (const float*)d_in[10], (const float*)d_in[14], (const float*)d_in[16],
        (const float*)d_in[5], (const float*)d_in[7], (const float*)d_in[9],
        (const float*)d_in[11], wt, bc, y, cnt, n);
    hist_kernel<<<1024, 256, 0, stream>>>(dstp, cnt, e);
    scan_block_sum<<<nb, 256, 0, stream>>>(cnt, bsum, n);
    scan_partials<<<1, 256, 0, stream>>>(bsum, bsumex, nb);
    scan_write<<<nb, 256, 0, stream>>>(cnt, bsumex, rowptr, cursor, n, e);
    scatter_kernel<<<1024, 256, 0, stream>>>(dstp, src, cursor, esrc, e);
    qkv_gemm<<<dim3(gr, 7), 256, 0, stream>>>(y, wt, bc, qkv, sx, n);
    attn_kernel<<<(n + 3) / 4, 256, 0, stream>>>(qkv, rowptr, esrc, x, sx,
                                                 (const float*)d_in[12],
                                                 (const float*)d_in[13], y, n);
    ffn_kernel<<<gr, 256, 0, stream>>>(y, wt + 114688, (const float*)d_in[15],
                                       wt + 131072, (const float*)d_in[17],
                                       sx, (float*)d_out, n);
}

// Round 12
// 416.458 us; speedup vs baseline: 1.0404x; 1.0404x over previous
//
#include <hip/hip_runtime.h>
#include <hip/hip_bf16.h>
#include <math.h>

// EncoderLayer_68186900791439 — graph transformer encoder layer on MI355X.
// Round 12: (a) attn 4-edges-per-slot (8 in flight/wave) — r11 showed VALU cut
// didn't move dur => gather-latency bound, so raise memory-level parallelism.
// (b) scatter fused into qkv_gemm as heterogeneous blocks (independent work,
// overlapped instead of serialized). 8 dispatches.

typedef unsigned short u16;
using short8 = __attribute__((ext_vector_type(8))) short;
using f32x4  = __attribute__((ext_vector_type(4))) float;
using f32x2  = __attribute__((ext_vector_type(2))) float;

__device__ __forceinline__ float bf2f(u16 u) {
    return __uint_as_float(((unsigned int)u) << 16);
}
__device__ __forceinline__ u16 f2bf(float f) {
    __hip_bfloat16 h = __float2bfloat16(f);
    return __builtin_bit_cast(u16, h);
}
__device__ __forceinline__ float bfe(short8 v, int j) {
    return bf2f((u16)v[j]);
}
// decode 4 packed fp8-e4m3 (one dword) -> 4 f32 (HW cvt, OCP on gfx950)
__device__ __forceinline__ void fp8x4_to_f32(int w, float* out) {
    f32x2 lo = __builtin_amdgcn_cvt_pk_f32_fp8(w, false);
    f32x2 hi = __builtin_amdgcn_cvt_pk_f32_fp8(w, true);
    out[0] = lo[0]; out[1] = lo[1]; out[2] = hi[0]; out[3] = hi[1];
}
// pack 4 f32 -> 4 fp8-e4m3 bytes in one dword
__device__ __forceinline__ unsigned pack_fp8x4(float4 f) {
    unsigned w = 0;
    w = (unsigned)__builtin_amdgcn_cvt_pk_fp8_f32(f.x, f.y, (int)w, false);
    w = (unsigned)__builtin_amdgcn_cvt_pk_fp8_f32(f.z, f.w, (int)w, true);
    return w;
}

// ============ Kernel A: prep weights + bias concat + LN1 + zero cnt ==========
__global__ __launch_bounds__(256) void fused_prep_ln(
    const float* __restrict__ x, const float* __restrict__ ln1g,
    const float* __restrict__ ln1b,
    const float* __restrict__ Wq, const float* __restrict__ Wk,
    const float* __restrict__ Wv, const float* __restrict__ Ws,
    const float* __restrict__ W1, const float* __restrict__ W2,
    const float* __restrict__ bq, const float* __restrict__ bk,
    const float* __restrict__ bv, const float* __restrict__ bs,
    u16* __restrict__ wt, float* __restrict__ bc,
    u16* __restrict__ y, int* __restrict__ cnt, int n)
{
    int gsz = gridDim.x * 256;
    int gtid = blockIdx.x * 256 + threadIdx.x;

    for (int i = gtid; i < 147456 + 896; i += gsz) {
        if (i < 147456) {
            const float* W; int N; int base;
            if      (i <  32768) { W = Wq; N = 256; base = 0; }
            else if (i <  65536) { W = Wk; N = 256; base = 32768; }
            else if (i <  98304) { W = Wv; N = 256; base = 65536; }
            else if (i < 114688) { W = Ws; N = 128; base = 98304; }
            else if (i < 131072) { W = W1; N = 128; base = 114688; }
            else                 { W = W2; N = 128; base = 131072; }
            int j = i - base;
            int nIdx = j >> 7, k = j & 127;
            wt[i] = f2bf(W[(size_t)k * N + nIdx]);
        } else {
            int j = i - 147456;
            float v;
            if      (j < 256) v = bq[j];
            else if (j < 512) v = bk[j - 256];
            else if (j < 768) v = bv[j - 512];
            else              v = bs[j - 768];
            bc[j] = v;
        }
    }
    for (int i = gtid; i < n; i += gsz) cnt[i] = 0;
    int lane = threadIdx.x & 63;
    int gw = gtid >> 6, nw = gsz >> 6;
    for (int row = gw; row < n; row += nw) {
        size_t base = (size_t)row * 128;
        float v0 = x[base + lane];
        float v1 = x[base + 64 + lane];
        float s1 = v0 + v1, s2 = v0 * v0 + v1 * v1;
        for (int o = 1; o <= 32; o <<= 1) {
            s1 += __shfl_xor(s1, o);
            s2 += __shfl_xor(s2, o);
        }
        float mu = s1 * (1.f / 128.f);
        float var = s2 * (1.f / 128.f) - mu * mu;
        float rstd = rsqrtf(var + 1e-5f);
        y[base + lane]      = f2bf((v0 - mu) * rstd * ln1g[lane] + ln1b[lane]);
        y[base + 64 + lane] = f2bf((v1 - mu) * rstd * ln1g[64 + lane] + ln1b[64 + lane]);
    }
}

// ============================ CSR build ====================================
__global__ __launch_bounds__(256) void hist_kernel(const int* __restrict__ dst,
                                                   int* __restrict__ cnt, int e) {
    int stride = gridDim.x * 256;
    for (int i = blockIdx.x * 256 + threadIdx.x; i < e; i += stride)
        atomicAdd(&cnt[dst[i]], 1);
}

__global__ __launch_bounds__(256) void scan_block_sum(const int* __restrict__ cnt,
                                                      int* __restrict__ bsum, int n) {
    __shared__ int s[256];
    int idx = blockIdx.x * 256 + threadIdx.x;
    s[threadIdx.x] = (idx < n) ? cnt[idx] : 0;
    __syncthreads();
    for (int o = 128; o > 0; o >>= 1) {
        if (threadIdx.x < o) s[threadIdx.x] += s[threadIdx.x + o];
        __syncthreads();
    }
    if (threadIdx.x == 0) bsum[blockIdx.x] = s[0];
}
__global__ __launch_bounds__(256) void scan_partials(const int* __restrict__ bsum,
                                                     int* __restrict__ bsumex, int nb) {
    __shared__ int s[256];
    int t = threadIdx.x;
    int v = (t < nb) ? bsum[t] : 0;
    s[t] = v;
    __syncthreads();
    for (int o = 1; o < 256; o <<= 1) {
        int add = (t >= o) ? s[t - o] : 0;
        __syncthreads();
        s[t] += add;
        __syncthreads();
    }
    bsumex[t] = s[t] - v;
}
__global__ __launch_bounds__(256) void scan_write(const int* __restrict__ cnt,
                                                  const int* __restrict__ bsumex,
                                                  int* __restrict__ rowptr,
                                                  int* __restrict__ cursor, int n, int etot) {
    __shared__ int s[256];
    int t = threadIdx.x;
    int idx = blockIdx.x * 256 + t;
    int v = (idx < n) ? cnt[idx] : 0;
    s[t] = v;
    __syncthreads();
    for (int o = 1; o < 256; o <<= 1) {
        int add = (t >= o) ? s[t - o] : 0;
        __syncthreads();
        s[t] += add;
        __syncthreads();
    }
    if (idx < n) {
        int ex = bsumex[blockIdx.x] + s[t] - v;
        rowptr[idx] = ex;
        cursor[idx] = ex;
    }
    if (idx == 0) rowptr[n] = etot;
}

// ====== MFMA GEMM qkv+skip + fused edge scatter (heterogeneous blocks) =======
// Blocks [0, gq*7): GEMM 64 rows x 128 cols. Blocks [gq*7, +scatBlocks):
// grid-stride scatter of src ids grouped by dst (independent work, overlapped
// here instead of a serialized dispatch).
__global__ __launch_bounds__(256) void qkv_gemm(
    const u16* __restrict__ A, const u16* __restrict__ Bt,
    const float* __restrict__ bias, u16* __restrict__ qkv,
    float* __restrict__ skip, int n, int gq,
    const int* __restrict__ dst, const int* __restrict__ src,
    int* __restrict__ cursor, int* __restrict__ esrc, int e, int scatBlocks)
{
    __shared__ float tile[64 * 132];                 // 33.8 KB
    int nGemm = gq * 7;
    if (blockIdx.x >= (unsigned)nGemm) {             // ---- scatter part ----
        int sb = blockIdx.x - nGemm;
        int stride = scatBlocks * 256;
        for (int i = sb * 256 + threadIdx.x; i < e; i += stride) {
            int p = atomicAdd(&cursor[dst[i]], 1);
            esrc[p] = src[i];
        }
        return;
    }
    int bx = blockIdx.x % gq;                        // ---- GEMM part ----
    int by = blockIdx.x / gq;
    int wid = threadIdx.x >> 6, lane = threadIdx.x & 63;
    int wr = wid >> 1, wc = wid & 1;
    int r0 = bx * 64;
    int c0 = by * 128;
    int lm = lane & 15, quad = lane >> 4;

    const u16* aBase = A  + (size_t)(r0 + wr * 32 + lm) * 128 + quad * 8;
    const u16* bBase = Bt + (size_t)(c0 + wc * 64 + lm) * 128 + quad * 8;

    f32x4 acc[2][4] = {};
#pragma unroll
    for (int kk = 0; kk < 128; kk += 32) {
        short8 a0 = *(const short8*)(aBase + kk);
        short8 a1 = *(const short8*)(aBase + 16 * 128 + kk);
#pragma unroll
        for (int j = 0; j < 4; ++j) {
            short8 bj = *(const short8*)(bBase + (size_t)j * 16 * 128 + kk);
            acc[0][j] = __builtin_amdgcn_mfma_f32_16x16x32_bf16(a0, bj, acc[0][j], 0, 0, 0);
            acc[1][j] = __builtin_amdgcn_mfma_f32_16x16x32_bf16(a1, bj, acc[1][j], 0, 0, 0);
        }
    }
#pragma unroll
    for (int j = 0; j < 4; ++j) {
        int colL = wc * 64 + j * 16 + lm;
        float bv = bias[c0 + colL];
#pragma unroll
        for (int rt = 0; rt < 2; ++rt) {
#pragma unroll
            for (int i2 = 0; i2 < 4; ++i2) {
                int rowL = wr * 32 + rt * 16 + quad * 4 + i2;
                tile[rowL * 132 + colL] = acc[rt][j][i2] + bv;
            }
        }
    }
    __syncthreads();

    int rowL = threadIdx.x >> 2;
    int row  = r0 + rowL;
    if (row >= n) return;
    int ck = (threadIdx.x & 3) * 32;
    int cg = c0 + ck;
    float4 f[8];
#pragma unroll
    for (int k = 0; k < 8; ++k)
        f[k] = *(const float4*)&tile[rowL * 132 + ck + k * 4];

    if (c0 < 256) {                                   // q bf16
        u16* dstp = qkv + (size_t)row * 640 + cg;
#pragma unroll
        for (int k = 0; k < 4; ++k) {
            short8 o;
            o[0] = (short)f2bf(f[2 * k].x);     o[1] = (short)f2bf(f[2 * k].y);
            o[2] = (short)f2bf(f[2 * k].z);     o[3] = (short)f2bf(f[2 * k].w);
            o[4] = (short)f2bf(f[2 * k + 1].x); o[5] = (short)f2bf(f[2 * k + 1].y);
            o[6] = (short)f2bf(f[2 * k + 1].z); o[7] = (short)f2bf(f[2 * k + 1].w);
            *(short8*)(dstp + k * 8) = o;
        }
    } else if (c0 < 512) {                            // k fp8 e4m3, packed
        unsigned char* kb = (unsigned char*)qkv + (size_t)row * 1280 + 512 + (cg - 256);
        uint4 w0, w1;
        w0.x = pack_fp8x4(f[0]); w0.y = pack_fp8x4(f[1]);
        w0.z = pack_fp8x4(f[2]); w0.w = pack_fp8x4(f[3]);
        w1.x = pack_fp8x4(f[4]); w1.y = pack_fp8x4(f[5]);
        w1.z = pack_fp8x4(f[6]); w1.w = pack_fp8x4(f[7]);
        *(uint4*)kb = w0;
        *(uint4*)(kb + 16) = w1;
    } else if (c0 < 768) {                            // v bf16
        u16* dstp = qkv + (size_t)row * 640 + (cg - 128);
#pragma unroll
        for (int k = 0; k < 4; ++k) {
            short8 o;
            o[0] = (short)f2bf(f[2 * k].x);     o[1] = (short)f2bf(f[2 * k].y);
            o[2] = (short)f2bf(f[2 * k].z);     o[3] = (short)f2bf(f[2 * k].w);
            o[4] = (short)f2bf(f[2 * k + 1].x); o[5] = (short)f2bf(f[2 * k + 1].y);
            o[6] = (short)f2bf(f[2 * k + 1].z); o[7] = (short)f2bf(f[2 * k + 1].w);
            *(short8*)(dstp + k * 8) = o;
        }
    } else {                                          // skip f32
        float* dstp = skip + (size_t)row * 128 + (cg - 768);
#pragma unroll
        for (int k = 0; k < 8; ++k)
            *(float4*)(dstp + k * 4) = f[k];
    }
}

// =============== Attention: wave per dst, 2 slots x 4-edge unroll ============
// No max-tracking (logits bounded with LN'd inputs; math identical to ref).
// Lane layout: slot=lane>>5, head=(lane>>4)&1, sub=lane&15. Lane owns 8 cols.
// 8 edges in flight per wave to cover L2-miss latency (r11: gather-bound).
__global__ __launch_bounds__(256) void attn_kernel(
    const u16* __restrict__ qkv, const int* __restrict__ rowptr,
    const int* __restrict__ esrc, const float* __restrict__ x,
    float* __restrict__ sx, const float* __restrict__ g2,
    const float* __restrict__ b2, u16* __restrict__ y, int n)
{
    int wid = threadIdx.x >> 6, lane = threadIdx.x & 63;
    int i = blockIdx.x * 4 + wid;
    if (i >= n) return;
    int slot = lane >> 5;
    int sub  = lane & 15;
    int colOff = ((lane >> 4) & 1) * 128 + sub * 8;

    const float scale = 0.08838834764831845f;   // 1/sqrt(128), folded into q
    short8 q8 = *(const short8*)(qkv + (size_t)i * 640 + colOff);
    float qf[8];
#pragma unroll
    for (int j = 0; j < 8; ++j) qf[j] = bfe(q8, j) * scale;

    int beg = rowptr[i], end = rowptr[i + 1];
    float l = 0.f;
    float acc[8] = {};

    int t = beg + slot;
    for (; t + 6 < end; t += 8) {               // 4 edges per slot in flight
        int s0 = esrc[t], s1 = esrc[t + 2], s2 = esrc[t + 4], s3 = esrc[t + 6];
        const u16* n0 = qkv + (size_t)s0 * 640;
        const u16* n1 = qkv + (size_t)s1 * 640;
        const u16* n2 = qkv + (size_t)s2 * 640;
        const u16* n3 = qkv + (size_t)s3 * 640;
        uint2 kw0 = *(const uint2*)((const unsigned char*)(n0 + 256) + colOff);
        uint2 kw1 = *(const uint2*)((const unsigned char*)(n1 + 256) + colOff);
        uint2 kw2 = *(const uint2*)((const unsigned char*)(n2 + 256) + colOff);
        uint2 kw3 = *(const uint2*)((const unsigned char*)(n3 + 256) + colOff);
        short8 v0 = *(const short8*)(n0 + 384 + colOff);
        short8 v1 = *(const short8*)(n1 + 384 + colOff);
        short8 v2 = *(const short8*)(n2 + 384 + colOff);
        short8 v3 = *(const short8*)(n3 + 384 + colOff);
        float k0f[8], k1f[8], k2f[8], k3f[8];
        fp8x4_to_f32((int)kw0.x, k0f); fp8x4_to_f32((int)kw0.y, k0f + 4);
        fp8x4_to_f32((int)kw1.x, k1f); fp8x4_to_f32((int)kw1.y, k1f + 4);
        fp8x4_to_f32((int)kw2.x, k2f); fp8x4_to_f32((int)kw2.y, k2f + 4);
        fp8x4_to_f32((int)kw3.x, k3f); fp8x4_to_f32((int)kw3.y, k3f + 4);
        float d0 = 0.f, d1 = 0.f, d2 = 0.f, d3 = 0.f;
#pragma unroll
        for (int j = 0; j < 8; ++j) {
            d0 += qf[j] * k0f[j];
            d1 += qf[j] * k1f[j];
            d2 += qf[j] * k2f[j];
            d3 += qf[j] * k3f[j];
        }
#pragma unroll
        for (int o = 1; o <= 8; o <<= 1) {      // reduce over 16-lane group
            d0 += __shfl_xor(d0, o);
            d1 += __shfl_xor(d1, o);
            d2 += __shfl_xor(d2, o);
            d3 += __shfl_xor(d3, o);
        }
        float w0 = __expf(d0), w1 = __expf(d1);
        float w2 = __expf(d2), w3 = __expf(d3);
        l += w0 + w1 + w2 + w3;
#pragma unroll
        for (int j = 0; j < 8; ++j)
            acc[j] += w0 * bfe(v0, j) + w1 * bfe(v1, j)
                    + w2 * bfe(v2, j) + w3 * bfe(v3, j);
    }
    for (; t < end; t += 2) {                    // slot tail: single edges
        int s0 = esrc[t];
        const u16* n0 = qkv + (size_t)s0 * 640;
        uint2 kw0 = *(const uint2*)((const unsigned char*)(n0 + 256) + colOff);
        short8 v0 = *(const short8*)(n0 + 384 + colOff);
        float k0f[8];
        fp8x4_to_f32((int)kw0.x, k0f); fp8x4_to_f32((int)kw0.y, k0f + 4);
        float d0 = 0.f;
#pragma unroll
        for (int j = 0; j < 8; ++j) d0 += qf[j] * k0f[j];
#pragma unroll
        for (int o = 1; o <= 8; o <<= 1) d0 += __shfl_xor(d0, o);
        float w0 = __expf(d0);
        l += w0;
#pragma unroll
        for (int j = 0; j < 8; ++j) acc[j] += w0 * bfe(v0, j);
    }

    // merge the two slots: plain adds (no rescale needed)
    l += __shfl_xor(l, 32);
    float inv = (l > 0.f) ? (1.f / l) : 0.f;
#pragma unroll
    for (int j = 0; j < 8; ++j) {
        acc[j] = (acc[j] + __shfl_xor(acc[j], 32)) * inv;
        acc[j] = 0.5f * (acc[j] + __shfl_xor(acc[j], 16));  // head mean
    }

    if (lane < 16) {                             // lanes 0..15 hold the row
        size_t base = (size_t)i * 128 + sub * 8;
        float4 xv0 = *(const float4*)(x + base);
        float4 xv1 = *(const float4*)(x + base + 4);
        float4 sk0 = *(const float4*)(sx + base);
        float4 sk1 = *(const float4*)(sx + base + 4);
        float r[8];
        r[0] = xv0.x + sk0.x + acc[0]; r[1] = xv0.y + sk0.y + acc[1];
        r[2] = xv0.z + sk0.z + acc[2]; r[3] = xv0.w + sk0.w + acc[3];
        r[4] = xv1.x + sk1.x + acc[4]; r[5] = xv1.y + sk1.y + acc[5];
        r[6] = xv1.z + sk1.z + acc[6]; r[7] = xv1.w + sk1.w + acc[7];
        *(float4*)(sx + base)     = make_float4(r[0], r[1], r[2], r[3]);
        *(float4*)(sx + base + 4) = make_float4(r[4], r[5], r[6], r[7]);
        float s1 = 0.f, s2 = 0.f;
#pragma unroll
        for (int j = 0; j < 8; ++j) { s1 += r[j]; s2 += r[j] * r[j]; }
#pragma unroll
        for (int o = 1; o <= 8; o <<= 1) {
            s1 += __shfl_xor(s1, o);
            s2 += __shfl_xor(s2, o);
        }
        float mu = s1 * (1.f / 128.f);
        float var = s2 * (1.f / 128.f) - mu * mu;
        float rstd = rsqrtf(var + 1e-5f);
        short8 o8;
#pragma unroll
        for (int j = 0; j < 8; ++j)
            o8[j] = (short)f2bf((r[j] - mu) * rstd * g2[sub * 8 + j] + b2[sub * 8 + j]);
        *(short8*)(y + base) = o8;
    }
}

// =============== Fused FFN: out = x2 + gelu(y2@W1T+b1)@W2T+b2 ===============
__global__ __launch_bounds__(256) void ffn_kernel(
    const u16* __restrict__ y2, const u16* __restrict__ W1T,
    const float* __restrict__ b1, const u16* __restrict__ W2T,
    const float* __restrict__ b2, const float* __restrict__ x2,
    float* __restrict__ out, int n)
{
    __shared__ u16 t1[64 * 136];
    int wid = threadIdx.x >> 6, lane = threadIdx.x & 63;
    int lm = lane & 15, quad = lane >> 4;
    int r0 = blockIdx.x * 64 + wid * 16;

    const u16* aBase = y2 + (size_t)(r0 + lm) * 128 + quad * 8;
    f32x4 acc[8] = {};
#pragma unroll
    for (int kk = 0; kk < 128; kk += 32) {
        short8 a0 = *(const short8*)(aBase + kk);
#pragma unroll
        for (int j = 0; j < 8; ++j) {
            short8 bj = *(const short8*)(W1T + (size_t)(j * 16 + lm) * 128 + quad * 8 + kk);
            acc[j] = __builtin_amdgcn_mfma_f32_16x16x32_bf16(a0, bj, acc[j], 0, 0, 0);
        }
    }
#pragma unroll
    for (int j = 0; j < 8; ++j) {
        int col = j * 16 + lm;
        float bv = b1[col];
#pragma unroll
        for (int i2 = 0; i2 < 4; ++i2) {
            int rl = wid * 16 + quad * 4 + i2;
            float v = acc[j][i2] + bv;
            v = 0.5f * v * (1.f + erff(v * 0.70710678118654752f));
            t1[rl * 136 + col] = f2bf(v);
        }
    }
    __syncthreads();

    f32x4 acc2[8] = {};
#pragma unroll
    for (int kk = 0; kk < 128; kk += 32) {
        short8 a0 = *(const short8*)(t1 + (wid * 16 + lm) * 136 + quad * 8 + kk);
#pragma unroll
        for (int j = 0; j < 8; ++j) {
            short8 bj = *(const short8*)(W2T + (size_t)(j * 16 + lm) * 128 + quad * 8 + kk);
            acc2[j] = __builtin_amdgcn_mfma_f32_16x16x32_bf16(a0, bj, acc2[j], 0, 0, 0);
        }
    }
#pragma unroll
    for (int j = 0; j < 8; ++j) {
        int col = j * 16 + lm;
        float bv = b2[col];
#pragma unroll
        for (int i2 = 0; i2 < 4; ++i2) {
            int row = r0 + quad * 4 + i2;
            if (row >= n) continue;
            size_t ob = (size_t)row * 128 + col;
            out[ob] = acc2[j][i2] + bv + x2[ob];
        }
    }
}

extern "C" void kernel_launch(void* const* d_in, const int* in_sizes, int n_in,
                              void* d_out, int out_size, void* d_ws, size_t ws_size,
                              hipStream_t stream)
{
    const float* x    = (const float*)d_in[0];
    const int*   ei   = (const int*)d_in[1];

    int n = in_sizes[0] / 128;     // 50000
    int e = in_sizes[1] / 2;       // 800000
    const int* src  = ei;          // edge_index[0] (messages src -> dst)
    const int* dstp = ei + e;      // edge_index[1]

    char* w = (char*)d_ws;
    size_t off = 0;
    auto alloc = [&](size_t bytes) -> void* {
        void* p = w + off;
        off = (off + bytes + 255) & ~(size_t)255;
        return p;
    };
    u16*   y    = (u16*)alloc((size_t)n * 128 * 2);   // LN1 out, then LN2 out
    u16*   qkv  = (u16*)alloc((size_t)n * 640 * 2);   // q bf16 | k fp8 | v bf16
    float* sx   = (float*)alloc((size_t)n * 128 * 4); // skip, then x2 in-place
    u16*   wt   = (u16*)alloc((size_t)147456 * 2);
    float* bc   = (float*)alloc(896 * 4);
    int* cnt    = (int*)alloc((size_t)n * 4);
    int* cursor = (int*)alloc((size_t)n * 4);
    int* rowptr = (int*)alloc(((size_t)n + 1) * 4);
    int* esrc   = (int*)alloc((size_t)e * 4);
    int* bsum   = (int*)alloc(1024);
    int* bsumex = (int*)alloc(1024);

    int gr  = (n + 63) / 64;       // row blocks (qkv + ffn)
    int nb  = (n + 255) / 256;     // scan chunks (196)
    int scatBlocks = 512;

    fused_prep_ln<<<2048, 256, 0, stream>>>(
        x, (const float*)d_in[2], (const float*)d_in[3],
        (const float*)d_in[4], (const float*)d_in[6], (const float*)d_in[8],
        (const float*)d_in[10], (const float*)d_in[14], (const float*)d_in[16],
        (const float*)d_in[5], (const float*)d_in[7], (const float*)d_in[9],
        (const float*)d_in[11], wt, bc, y, cnt, n);
    hist_kernel<<<1024, 256, 0, stream>>>(dstp, cnt, e);
    scan_block_sum<<<nb, 256, 0, stream>>>(cnt, bsum, n);
    scan_partials<<<1, 256, 0, stream>>>(bsum, bsumex, nb);
    scan_write<<<nb, 256, 0, stream>>>(cnt, bsumex, rowptr, cursor, n, e);
    // GEMM + overlapped scatter (independent: cursor ready, y ready)
    qkv_gemm<<<gr * 7 + scatBlocks, 256, 0, stream>>>(
        y, wt, bc, qkv, sx, n, gr, dstp, src, cursor, esrc, e, scatBlocks);
    attn_kernel<<<(n + 3) / 4, 256, 0, stream>>>(qkv, rowptr, esrc, x, sx,
                                                 (const float*)d_in[12],
                                                 (const float*)d_in[13], y, n);
    ffn_kernel<<<gr, 256, 0, stream>>>(y, wt + 114688, (const float*)d_in[15],
                                       wt + 131072, (const float*)d_in[17],
                                       sx, (float*)d_out, n);
}